// Round 1
// baseline (273.625 us; speedup 1.0000x reference)
//
#include <hip/hip_runtime.h>

// FullAttention: O[b,l,h,d] = softmax_s( scale * Q[b,l,h,:]·K[b,s,h,:] ) @ V[b,s,h,:]
// B=4, L=S=2048, H=8, E=D=64, fp32 in/out, bf16 MFMA compute (harness threshold is bf16-eps).

#define B_ 4
#define L_ 2048
#define S_ 2048
#define H_ 8
#define E_ 64
#define D_ 64

typedef __attribute__((ext_vector_type(8))) __bf16 bf16x8;
typedef __attribute__((ext_vector_type(4))) float floatx4;

#define KSTRIDE 72  // bf16 per K_lds row: 64 + 8 pad -> 144 B row (16B aligned, bank-spread)
#define VSTRIDE 40  // bf16 per Vt_lds row: 32 + 8 pad -> 80 B row (16B aligned)
#define PSTRIDE 40  // bf16 per P_lds row: 32 + 8 pad

__global__ __launch_bounds__(256) void attn_kernel(const float* __restrict__ Q,
                                                   const float* __restrict__ K,
                                                   const float* __restrict__ V,
                                                   float* __restrict__ O) {
  __shared__ __align__(16) __bf16 K_lds[32 * KSTRIDE];       // 32 keys x 64 (E)
  __shared__ __align__(16) __bf16 Vt_lds[64 * VSTRIDE];      // 64 d x 32 s  (transposed)
  __shared__ __align__(16) __bf16 P_lds[4 * 16 * PSTRIDE];   // per-wave 16 q x 32 s

  const int tid = threadIdx.x;
  const int lane = tid & 63;
  const int wave = tid >> 6;
  const int n16 = lane & 15;
  const int quad = lane >> 4;

  const int bid = blockIdx.x;
  const int qb = bid & 31;        // 32 q-blocks of 64 rows
  const int h = (bid >> 5) & 7;
  const int b = bid >> 8;

  // ---- Q fragment (A-operand layout: m = lane&15, k = quad*8 + j), scale*log2e folded in
  const float qscale = 0.125f * 1.44269504088896340736f;  // 1/sqrt(64) * log2(e)
  const int qrow = qb * 64 + wave * 16 + n16;
  const float* qp = Q + ((size_t)(b * L_ + qrow) * H_ + h) * E_;
  bf16x8 qf0, qf1;
  {
    float4 a0 = *(const float4*)(qp + quad * 8);
    float4 a1 = *(const float4*)(qp + quad * 8 + 4);
    float4 b0 = *(const float4*)(qp + 32 + quad * 8);
    float4 b1 = *(const float4*)(qp + 32 + quad * 8 + 4);
    float t0[8] = {a0.x, a0.y, a0.z, a0.w, a1.x, a1.y, a1.z, a1.w};
    float t1[8] = {b0.x, b0.y, b0.z, b0.w, b1.x, b1.y, b1.z, b1.w};
#pragma unroll
    for (int j = 0; j < 8; ++j) {
      qf0[j] = (__bf16)(t0[j] * qscale);
      qf1[j] = (__bf16)(t1[j] * qscale);
    }
  }

  // ---- online-softmax state (C-layout rows: q = quad*4 + r)
  float m[4], l[4];
  floatx4 o[4];  // d chunks 0..3 (cols dc*16 + n16)
#pragma unroll
  for (int r = 0; r < 4; ++r) { m[r] = -1e30f; l[r] = 0.0f; }
#pragma unroll
  for (int dc = 0; dc < 4; ++dc) o[dc] = (floatx4){0.f, 0.f, 0.f, 0.f};

  // ---- staging index precompute
  const int kr = tid >> 3;        // key row 0..31
  const int kc = (tid & 7) * 8;   // col base 0..56
  const float* kbase = K + ((size_t)b * S_ * H_ + h) * E_;
  const int vs = tid & 31;        // s row 0..31
  const int vd = (tid >> 5) * 8;  // d base 0..56
  const float* vbase = V + ((size_t)b * S_ * H_ + h) * D_;

  __bf16* Pw = &P_lds[wave * 16 * PSTRIDE];

  for (int ks = 0; ks < S_; ks += 32) {
    // ---- stage K tile (row-major bf16, vector 16B LDS writes)
    {
      const float* gk = kbase + (size_t)(ks + kr) * H_ * E_ + kc;
      float4 f0 = *(const float4*)gk;
      float4 f1 = *(const float4*)(gk + 4);
      bf16x8 kv;
      kv[0] = (__bf16)f0.x; kv[1] = (__bf16)f0.y; kv[2] = (__bf16)f0.z; kv[3] = (__bf16)f0.w;
      kv[4] = (__bf16)f1.x; kv[5] = (__bf16)f1.y; kv[6] = (__bf16)f1.z; kv[7] = (__bf16)f1.w;
      *(bf16x8*)&K_lds[kr * KSTRIDE + kc] = kv;
    }
    // ---- stage V tile transposed: Vt[d][s]
    {
      const float* gv = vbase + (size_t)(ks + vs) * H_ * D_ + vd;
      float4 f0 = *(const float4*)gv;
      float4 f1 = *(const float4*)(gv + 4);
      float vals[8] = {f0.x, f0.y, f0.z, f0.w, f1.x, f1.y, f1.z, f1.w};
#pragma unroll
      for (int j = 0; j < 8; ++j) Vt_lds[(vd + j) * VSTRIDE + vs] = (__bf16)vals[j];
    }
    __syncthreads();

    // ---- scores: S[16q x 32k] = Q(16x64) * K^T  (two 16x16 tiles, K=32 chunks)
    floatx4 sc0 = (floatx4){0.f, 0.f, 0.f, 0.f};
    floatx4 sc1 = (floatx4){0.f, 0.f, 0.f, 0.f};
    {
      bf16x8 k00 = *(const bf16x8*)&K_lds[n16 * KSTRIDE + quad * 8];
      bf16x8 k01 = *(const bf16x8*)&K_lds[n16 * KSTRIDE + 32 + quad * 8];
      bf16x8 k10 = *(const bf16x8*)&K_lds[(16 + n16) * KSTRIDE + quad * 8];
      bf16x8 k11 = *(const bf16x8*)&K_lds[(16 + n16) * KSTRIDE + 32 + quad * 8];
      sc0 = __builtin_amdgcn_mfma_f32_16x16x32_bf16(qf0, k00, sc0, 0, 0, 0);
      sc0 = __builtin_amdgcn_mfma_f32_16x16x32_bf16(qf1, k01, sc0, 0, 0, 0);
      sc1 = __builtin_amdgcn_mfma_f32_16x16x32_bf16(qf0, k10, sc1, 0, 0, 0);
      sc1 = __builtin_amdgcn_mfma_f32_16x16x32_bf16(qf1, k11, sc1, 0, 0, 0);
    }

    // ---- online softmax (rows q = quad*4 + r; 16 lanes of the quad share a row)
#pragma unroll
    for (int r = 0; r < 4; ++r) {
      float t = fmaxf(sc0[r], sc1[r]);
      t = fmaxf(t, __shfl_xor(t, 1));
      t = fmaxf(t, __shfl_xor(t, 2));
      t = fmaxf(t, __shfl_xor(t, 4));
      t = fmaxf(t, __shfl_xor(t, 8));
      float mn = fmaxf(m[r], t);
      float alpha = exp2f(m[r] - mn);
      float p0 = exp2f(sc0[r] - mn);
      float p1 = exp2f(sc1[r] - mn);
      float rs = p0 + p1;
      rs += __shfl_xor(rs, 1);
      rs += __shfl_xor(rs, 2);
      rs += __shfl_xor(rs, 4);
      rs += __shfl_xor(rs, 8);
      m[r] = mn;
      l[r] = l[r] * alpha + rs;
      o[0][r] *= alpha; o[1][r] *= alpha; o[2][r] *= alpha; o[3][r] *= alpha;
      // P (C-layout) -> LDS for layout transform to A-operand
      Pw[(quad * 4 + r) * PSTRIDE + n16] = (__bf16)p0;
      Pw[(quad * 4 + r) * PSTRIDE + 16 + n16] = (__bf16)p1;
    }

    // wave-local LDS write->read ordering (P_lds is per-wave; DS ops are in-order per wave)
    asm volatile("s_waitcnt lgkmcnt(0)" ::: "memory");

    // ---- PV: O[16q x 64d] += P(16x32) * V(32x64)
    {
      bf16x8 pf = *(const bf16x8*)&Pw[n16 * PSTRIDE + quad * 8];  // A: m=lane&15, k=quad*8+j
#pragma unroll
      for (int dc = 0; dc < 4; ++dc) {
        bf16x8 vf = *(const bf16x8*)&Vt_lds[(dc * 16 + n16) * VSTRIDE + quad * 8];  // B: n=lane&15, k=quad*8+j
        o[dc] = __builtin_amdgcn_mfma_f32_16x16x32_bf16(pf, vf, o[dc], 0, 0, 0);
      }
    }
    __syncthreads();  // K_lds/Vt_lds reads done before next stage overwrites
  }

  // ---- epilogue: O[b, qb*64 + wave*16 + q, h, d] = o/l
  float* ob = O + ((size_t)(b * L_ + qb * 64 + wave * 16) * H_ + h) * D_;
#pragma unroll
  for (int r = 0; r < 4; ++r) {
    float inv = 1.0f / l[r];
    int row = quad * 4 + r;
    float* orow = ob + (size_t)row * H_ * D_;
#pragma unroll
    for (int dc = 0; dc < 4; ++dc) orow[dc * 16 + n16] = o[dc][r] * inv;
  }
}

extern "C" void kernel_launch(void* const* d_in, const int* in_sizes, int n_in,
                              void* d_out, int out_size, void* d_ws, size_t ws_size,
                              hipStream_t stream) {
  const float* Q = (const float*)d_in[0];
  const float* K = (const float*)d_in[1];
  const float* V = (const float*)d_in[2];
  float* O = (float*)d_out;
  // grid: b(4) x h(8) x qblock(32) = 1024 blocks, 256 threads (4 waves x 16 queries)
  dim3 grid(B_ * H_ * (L_ / 64));
  attn_kernel<<<grid, 256, 0, stream>>>(Q, K, V, O);
}

// Round 3
// 160.291 us; speedup vs baseline: 1.7071x; 1.7071x over previous
//
#include <hip/hip_runtime.h>

// FullAttention: O[b,l,h,d] = softmax_s( scale * Q[b,l,h,:]·K[b,s,h,:] ) @ V[b,s,h,:]
// B=4, L=S=2048, H=8, E=D=64, fp32 in/out, bf16 MFMA compute.
// R3: double-buffered K/V LDS so the P LDS round-trip is ordered by a real
//     __syncthreads() (R2's inline-asm waitcnt ordering was the non-determinism
//     suspect). Global loads for tile t+1 issued before compute of tile t
//     (latency hidden under QK+softmax). Max-free softmax, packed π-permuted
//     P/V writes (2-way bank conflicts only = free).

#define B_ 4
#define L_ 2048
#define S_ 2048
#define H_ 8
#define E_ 64
#define D_ 64

typedef __attribute__((ext_vector_type(8))) __bf16 bf16x8;
typedef __attribute__((ext_vector_type(2))) __bf16 bf16x2;
typedef __attribute__((ext_vector_type(4))) float floatx4;

#define KSTR 72  // bf16/row K_lds: 64 + 8 pad = 144 B
#define VSTR 40  // bf16/row Vt_lds: 32 + 8 pad = 80 B
#define PSTR 40  // bf16/row P_lds:  32 + 8 pad = 80 B

__device__ __forceinline__ bf16x8 cvt8(float4 a, float4 b) {
  bf16x8 r;
  r[0] = (__bf16)a.x; r[1] = (__bf16)a.y; r[2] = (__bf16)a.z; r[3] = (__bf16)a.w;
  r[4] = (__bf16)b.x; r[5] = (__bf16)b.y; r[6] = (__bf16)b.z; r[7] = (__bf16)b.w;
  return r;
}

__global__ __launch_bounds__(256) void attn_kernel(const float* __restrict__ Q,
                                                   const float* __restrict__ K,
                                                   const float* __restrict__ V,
                                                   float* __restrict__ O) {
  __shared__ __align__(16) __bf16 K_lds[2][32 * KSTR];   // dbuf: 32 keys x 64 e
  __shared__ __align__(16) __bf16 Vt_lds[2][64 * VSTR];  // dbuf: 64 d x 32 kpos (π-permuted s)
  __shared__ __align__(16) __bf16 P_lds[4 * 16 * PSTR];  // per-wave 16 q x 32 kpos

  const int tid = threadIdx.x;
  const int lane = tid & 63;
  const int wave = tid >> 6;
  const int n16 = lane & 15;
  const int quad = lane >> 4;

  const int bid = blockIdx.x;
  const int qb = bid & 31;
  const int h = (bid >> 5) & 7;
  const int b = bid >> 8;

  // ---- Q fragment (A-layout: m=lane&15, k=quad*8+j), scale*log2e folded in
  const float qscale = 0.125f * 1.44269504088896340736f;
  const int qrow = qb * 64 + wave * 16 + n16;
  const float* qp = Q + ((size_t)(b * L_ + qrow) * H_ + h) * E_;
  bf16x8 qf0, qf1;
  {
    float4 a0 = *(const float4*)(qp + quad * 8);
    float4 a1 = *(const float4*)(qp + quad * 8 + 4);
    float4 b0 = *(const float4*)(qp + 32 + quad * 8);
    float4 b1 = *(const float4*)(qp + 32 + quad * 8 + 4);
    bf16x8 q0 = cvt8(a0, a1), q1 = cvt8(b0, b1);
#pragma unroll
    for (int j = 0; j < 8; ++j) {
      qf0[j] = (__bf16)((float)q0[j] * qscale);
      qf1[j] = (__bf16)((float)q1[j] * qscale);
    }
  }

  // ---- state
  float l[4];
  floatx4 o[4];
#pragma unroll
  for (int r = 0; r < 4; ++r) l[r] = 0.0f;
#pragma unroll
  for (int dc = 0; dc < 4; ++dc) o[dc] = (floatx4){0.f, 0.f, 0.f, 0.f};

  // ---- staging indices
  const int kr = tid >> 3;         // K row 0..31
  const int kc = (tid & 7) * 8;    // K col base
  const float* kbase = K + ((size_t)b * S_ * H_ + h) * E_;
  const int vu = tid & 15;         // V row pair (u, u+16)
  const int vdb = (tid >> 4) * 4;  // V d base 0..60
  const float* vbase = V + ((size_t)b * S_ * H_ + h) * D_;

  __bf16* Pw = &P_lds[wave * 16 * PSTR];

  // ---- prologue: stage tile 0 into buf 0
  {
    const float* gk = kbase + (size_t)kr * H_ * E_ + kc;
    float4 ka = *(const float4*)gk;
    float4 kb = *(const float4*)(gk + 4);
    *(bf16x8*)&K_lds[0][kr * KSTR + kc] = cvt8(ka, kb);
    const float* gv = vbase + (size_t)vu * H_ * D_ + vdb;
    float4 va = *(const float4*)gv;
    float4 vb = *(const float4*)(gv + 16 * H_ * D_);
    float lo[4] = {va.x, va.y, va.z, va.w};
    float hi[4] = {vb.x, vb.y, vb.z, vb.w};
#pragma unroll
    for (int j = 0; j < 4; ++j) {
      bf16x2 pp = {(__bf16)lo[j], (__bf16)hi[j]};
      *(bf16x2*)&Vt_lds[0][(vdb + j) * VSTR + 2 * vu] = pp;
    }
  }

  const int NT = S_ / 32;
  for (int t = 0; t < NT; ++t) {
    const int buf = t & 1;
    __syncthreads();  // sync0: staging of buf visible; prev iter's PV reads of buf^1 done

    // ---- issue global loads for tile t+1 (consumed after the compute phase)
    float4 ka, kb, va, vb;
    const bool stage = (t + 1 < NT);
    if (stage) {
      const int ks2 = (t + 1) * 32;
      const float* gk = kbase + (size_t)(ks2 + kr) * H_ * E_ + kc;
      ka = *(const float4*)gk;
      kb = *(const float4*)(gk + 4);
      const float* gv = vbase + (size_t)(ks2 + vu) * H_ * D_ + vdb;
      va = *(const float4*)gv;
      vb = *(const float4*)(gv + 16 * H_ * D_);
    }

    // ---- QK: S[16q x 32k] (two 16x16 tiles, E=64 in two K=32 chunks)
    floatx4 sc0 = (floatx4){0.f, 0.f, 0.f, 0.f};
    floatx4 sc1 = (floatx4){0.f, 0.f, 0.f, 0.f};
    {
      const __bf16* Kb = K_lds[buf];
      bf16x8 k00 = *(const bf16x8*)&Kb[n16 * KSTR + quad * 8];
      bf16x8 k01 = *(const bf16x8*)&Kb[n16 * KSTR + 32 + quad * 8];
      bf16x8 k10 = *(const bf16x8*)&Kb[(16 + n16) * KSTR + quad * 8];
      bf16x8 k11 = *(const bf16x8*)&Kb[(16 + n16) * KSTR + 32 + quad * 8];
      sc0 = __builtin_amdgcn_mfma_f32_16x16x32_bf16(qf0, k00, sc0, 0, 0, 0);
      sc0 = __builtin_amdgcn_mfma_f32_16x16x32_bf16(qf1, k01, sc0, 0, 0, 0);
      sc1 = __builtin_amdgcn_mfma_f32_16x16x32_bf16(qf0, k10, sc1, 0, 0, 0);
      sc1 = __builtin_amdgcn_mfma_f32_16x16x32_bf16(qf1, k11, sc1, 0, 0, 0);
    }

    // ---- max-free softmax numerators; packed P write (kpos 2*n16, 2*n16+1)
#pragma unroll
    for (int r = 0; r < 4; ++r) {
      float p0 = __builtin_amdgcn_exp2f(sc0[r]);
      float p1 = __builtin_amdgcn_exp2f(sc1[r]);
      l[r] += p0 + p1;
      bf16x2 pp = {(__bf16)p0, (__bf16)p1};
      *(bf16x2*)&Pw[(quad * 4 + r) * PSTR + 2 * n16] = pp;
    }

    // ---- stage tile t+1 into buf^1 (vmcnt wait lands here, hidden under QK+softmax)
    if (stage) {
      *(bf16x8*)&K_lds[buf ^ 1][kr * KSTR + kc] = cvt8(ka, kb);
      float lo[4] = {va.x, va.y, va.z, va.w};
      float hi[4] = {vb.x, vb.y, vb.z, vb.w};
#pragma unroll
      for (int j = 0; j < 4; ++j) {
        bf16x2 pp = {(__bf16)lo[j], (__bf16)hi[j]};
        *(bf16x2*)&Vt_lds[buf ^ 1][(vdb + j) * VSTR + 2 * vu] = pp;
      }
    }

    __syncthreads();  // sync1: P visible (real barrier, not asm); staging of buf^1 done

    // ---- PV: O[16q x 64d] += P_perm(16x32) * V_perm(32x64)
    {
      bf16x8 pf = *(const bf16x8*)&Pw[n16 * PSTR + quad * 8];
      const __bf16* Vb = Vt_lds[buf];
#pragma unroll
      for (int dc = 0; dc < 4; ++dc) {
        bf16x8 vfr = *(const bf16x8*)&Vb[(dc * 16 + n16) * VSTR + quad * 8];
        o[dc] = __builtin_amdgcn_mfma_f32_16x16x32_bf16(pf, vfr, o[dc], 0, 0, 0);
      }
    }
  }

  // ---- epilogue: reduce l across the 16-lane row group, normalize, store
  float* ob = O + ((size_t)(b * L_ + qb * 64 + wave * 16) * H_ + h) * D_;
#pragma unroll
  for (int r = 0; r < 4; ++r) {
    float lr = l[r];
    lr += __shfl_xor(lr, 1);
    lr += __shfl_xor(lr, 2);
    lr += __shfl_xor(lr, 4);
    lr += __shfl_xor(lr, 8);
    float inv = 1.0f / lr;
    float* orow = ob + (size_t)(quad * 4 + r) * H_ * D_;
#pragma unroll
    for (int dc = 0; dc < 4; ++dc) orow[dc * 16 + n16] = o[dc][r] * inv;
  }
}

extern "C" void kernel_launch(void* const* d_in, const int* in_sizes, int n_in,
                              void* d_out, int out_size, void* d_ws, size_t ws_size,
                              hipStream_t stream) {
  const float* Q = (const float*)d_in[0];
  const float* K = (const float*)d_in[1];
  const float* V = (const float*)d_in[2];
  float* O = (float*)d_out;
  dim3 grid(B_ * H_ * (L_ / 64));  // 1024 blocks, 4 waves x 16 queries each
  attn_kernel<<<grid, 256, 0, stream>>>(Q, K, V, O);
}